// Round 6
// baseline (29.643 us; speedup 1.0000x reference)
//
#include <hip/hip_runtime.h>

// PS-RoIAlign forward, fp32 — round 6: temporally phased channels for L2 hits.
//
// Round-5 diagnosis: ~6.3 line-req/cyc/XCD == 7.7 TB/s behind L2; per-XCD
// working set 20 MB >> 4 MB L2 (all channels live at once), so the L2-miss
// path (MSHR/LLC) caps throughput. Neither MLP nor request count moved it.
//
// Fix: per XCD, sweep its 64-channel chunk in 4 sequential PHASES of 16
// channels. Phase footprint = 16 ch x 8 batches x 40 KB = 5 MB ~ L2, so
// intra-phase re-reads (all 2048 rois touch each channel) become L2 hits.
// All 16K threads of an XCD work the SAME 16 channels concurrently:
//   thread t (xcd-local) -> roi k = t & 2047, pair = t >> 11 (0..7)
//   phase p -> channels cbase = xcd*64 + p*16 + pair*2, +1
// Stores: one phase writes exactly one 64B line per roi-row (16 ch x 4B),
// as 8x 8B pieces within the phase window -> L2 merges them.
//
// input [8,490,100,100] fp32, rois [2048,5], out [2048,490]

#define PSR_C  490
#define PSR_H  100
#define PSR_W  100
#define PSR_HW (PSR_H * PSR_W)
#define PSR_SC 0.0625f

typedef float f4v __attribute__((ext_vector_type(4), aligned(4)));
typedef float f2v __attribute__((ext_vector_type(2), aligned(4)));

__device__ __forceinline__ f4v ld4(const float* p) { return *(const f4v*)p; }

// select element e (0..2) / e+1 from a 4-wide window
__device__ __forceinline__ float sel3(float a0, float a1, float a2, int e) {
    float r = (e == 1) ? a1 : a0;
    return (e == 2) ? a2 : r;
}

__global__ __launch_bounds__(256) void PSRoIAlign_72069551227028_kernel(
    const float* __restrict__ input,
    const float* __restrict__ rois,
    float* __restrict__ out)
{
    const int tid  = threadIdx.x;
    const int xcd  = blockIdx.x & 7;    // HW round-robins blocks over XCDs
    const int u    = blockIdx.x >> 3;   // 0..63 (64 blocks per XCD, 2/CU)
    const int t    = u * 256 + tid;     // 0..16383 xcd-local thread
    const int k    = t & 2047;          // roi
    const int pair = t >> 11;           // 0..7 channel pair within phase

    // ---- per-roi params (fixed for the whole thread) ----
    f4v rv4 = ld4(rois + k * 5);
    const int   b  = (int)rv4.x;
    const float sw = rv4.y * PSR_SC - 0.5f;
    const float sh = rv4.z * PSR_SC - 0.5f;
    const float ew = rv4.w * PSR_SC - 0.5f;
    const float eh = rois[k * 5 + 4] * PSR_SC - 0.5f;
    const float bin_w = fmaxf(ew - sw, 0.1f) * (1.0f / 7.0f);
    const float bin_h = fmaxf(eh - sh, 0.1f) * (1.0f / 7.0f);
    const float* bb = input + (size_t)b * (PSR_C * PSR_HW);

    float* const orow = out + (size_t)k * PSR_C;

    for (int p = 0; p < 4; ++p) {
        const int cbase = xcd * 64 + p * 16 + pair * 2;  // even; may pad >=490

        // ---- phase 1: params + issue all loads for 2 channels ----
        f4v   w[2][4];
        float ex[2][4];
        float wx[2][4], wy[2][4];
        int   e0a[2], e1a[2], da[2];

#pragma unroll
        for (int g = 0; g < 2; ++g) {
            const int c  = cbase + g;
            const int cv = (c < PSR_C);
            const int ca = cv ? c : (PSR_C - 1);   // safe addressing for pads
            const int s49 = ca % 49;
            const int ph  = s49 / 7;
            const int pw  = s49 - ph * 7;

            int yb[2], xb[2];
#pragma unroll
            for (int i = 0; i < 2; ++i) {
                const float off = (i + 0.5f) * 0.5f;

                float y  = sh + ((float)ph + off) * bin_h;
                float my = (y >= -1.0f && y <= (float)PSR_H) ? 0.25f : 0.0f;
                if (!cv) my = 0.0f;
                float cy = fmaxf(y, 0.0f);
                int lo = min((int)cy, PSR_H - 1);
                float fr = cy - (float)lo;
                if (lo >= PSR_H - 1) { yb[i] = PSR_H - 2; wy[g][2*i] = 0.0f;             wy[g][2*i+1] = my;      }
                else                 { yb[i] = lo;        wy[g][2*i] = my * (1.0f - fr); wy[g][2*i+1] = my * fr; }

                float x  = sw + ((float)pw + off) * bin_w;
                float mx = (x >= -1.0f && x <= (float)PSR_W) ? 1.0f : 0.0f;
                float cx = fmaxf(x, 0.0f);
                int lox = min((int)cx, PSR_W - 1);
                float frx = cx - (float)lox;
                if (lox >= PSR_W - 1) { xb[i] = PSR_W - 2; wx[g][2*i] = 0.0f;              wx[g][2*i+1] = mx;       }
                else                  { xb[i] = lox;       wx[g][2*i] = mx * (1.0f - frx); wx[g][2*i+1] = mx * frx; }
            }

            const int xs = min(xb[0], PSR_W - 4);
            const int d  = yb[1] - yb[0];
            const int o0 = ca * PSR_HW + yb[0] * PSR_W + xs;
            const int o2 = ca * PSR_HW + yb[1] * PSR_W + xs;
            e0a[g] = xb[0] - xs;     // 0..2
            e1a[g] = xb[1] - xs;     // 0..3 (3 rare)
            da[g]  = d;

            w[g][0] = ld4(bb + o0);
            w[g][1] = ld4(bb + o0 + PSR_W);
            if (d >= 2) w[g][2] = ld4(bb + o2);          // exec-masked
            if (d >= 1) w[g][3] = ld4(bb + o2 + PSR_W);  // exec-masked

            ex[g][0] = 0.f; ex[g][1] = 0.f; ex[g][2] = 0.f; ex[g][3] = 0.f;
            if (e1a[g] > 2) {        // rare far x-sample: one scalar per row
                ex[g][0] = bb[o0 + 4];
                ex[g][1] = bb[o0 + PSR_W + 4];
                ex[g][2] = bb[o2 + 4];
                ex[g][3] = bb[o2 + PSR_W + 4];
            }
        }

        // ---- phase 2: consume ----
        float acc[2];
#pragma unroll
        for (int g = 0; g < 2; ++g) {
            const int e0 = e0a[g], e1 = e1a[g], d = da[g];
            const bool far = (e1 > 2);

            f4v w0 = w[g][0], w1 = w[g][1];
            f4v w2 = (d == 0) ? w0 : ((d == 1) ? w1 : w[g][2]);
            f4v w3 = (d == 0) ? w1 : w[g][3];

            const f4v wrow[4] = { w0, w1, w2, w3 };
            float rsum[4];
#pragma unroll
            for (int rr = 0; rr < 4; ++rr) {
                const f4v ww = wrow[rr];
                float s0l = sel3(ww.x, ww.y, ww.z, e0);
                float s0h = sel3(ww.y, ww.z, ww.w, e0);
                float s1l = far ? ww.w      : sel3(ww.x, ww.y, ww.z, e1);
                float s1h = far ? ex[g][rr] : sel3(ww.y, ww.z, ww.w, e1);
                rsum[rr] = (s0l * wx[g][0] + s0h * wx[g][1])
                         + (s1l * wx[g][2] + s1h * wx[g][3]);
            }
            acc[g] = wy[g][0] * rsum[0] + wy[g][1] * rsum[1]
                   + wy[g][2] * rsum[2] + wy[g][3] * rsum[3];
        }

        // ---- store: 8B (two consecutive channels); skip pad pairs ----
        if (cbase + 1 < PSR_C) {          // cbase even, so full pair or none
            f2v a { acc[0], acc[1] };
            *(f2v*)(orow + cbase) = a;
        }
    }
}

extern "C" void kernel_launch(void* const* d_in, const int* in_sizes, int n_in,
                              void* d_out, int out_size, void* d_ws, size_t ws_size,
                              hipStream_t stream) {
    const float* input = (const float*)d_in[0];
    const float* rois  = (const float*)d_in[1];
    float* out = (float*)d_out;

    PSRoIAlign_72069551227028_kernel<<<512, 256, 0, stream>>>(input, rois, out);
}